// Round 9
// baseline (23.862 us; speedup 1.0000x reference)
//
#include <hip/hip_runtime.h>

#define NBINS 256
#define ROWS 96                    // b*c = 32*3
#define ROW_N (512 * 512)          // 262144 elements per row
#define BPR 8                      // blocks per row
#define CHUNK (ROW_N / BPR)        // 32768 elements per block
#define BLOCK 512
#define WAVES (BLOCK / 64)         // 8
#define BIN_W 0.99609375f          // (255-0)/256, exactly representable
#define RECIP_W 1.00392156862745098f  // fl(256/255)

#define PART_WORDS ((size_t)ROWS * BPR * NBINS)   // 196608 u32 partials
#define CTR_OFF PART_WORDS                        // ctr[ROWS]
#define BASE_OFF (PART_WORDS + 256)               // base[ROWS], separate lines
#define WS_NEEDED ((BASE_OFF + ROWS) * sizeof(unsigned int))

#define ATOMIC_LD(p) __hip_atomic_load((p), __ATOMIC_RELAXED, __HIP_MEMORY_SCOPE_AGENT)
#define ATOMIC_ST(p, v) __hip_atomic_store((p), (v), __ATOMIC_RELAXED, __HIP_MEMORY_SCOPE_AGENT)

// exact floor(fv / BIN_W) without v_div: multiply-estimate + exact fixup.
// bf*BIN_W and (bf+1)*BIN_W are EXACT in fp32 (b <= 256 -> b*255 < 2^17),
// so the compares compute the true floor. Verified bit-exact (R3-R8 absmax=0).
__device__ __forceinline__ void bin_hit(float fv, unsigned int* lhw) {
    float bf = truncf(fv * RECIP_W);
    float t = bf * BIN_W;
    int b = (int)bf + (int)((t + BIN_W) <= fv) - (int)(t > fv);
    b = b > NBINS - 1 ? NBINS - 1 : b;        // also maps fv==255 -> 255
    bool valid = (fv >= 0.0f) && (fv <= 255.0f);   // NaN -> false
    atomicAdd(&lhw[valid ? b : NBINS], 1u);   // invalid -> trash slot
}

// ==== fused: LDS hist + fence-free per-row finisher (no L2 writebacks) ====
template <bool USE_WS>
__global__ __launch_bounds__(BLOCK) void nh_hist(const float* __restrict__ x,
                                                 unsigned int* __restrict__ ws,
                                                 float* __restrict__ out) {
    __shared__ unsigned int lh[WAVES][NBINS + 1];   // +1 = trash for invalid
    __shared__ unsigned int s_old;
    __shared__ int s_fin;
    const int tid = threadIdx.x;
    unsigned int* lhw = lh[tid >> 6];

    #pragma unroll
    for (int i = tid; i < WAVES * (NBINS + 1); i += BLOCK)
        ((unsigned int*)lh)[i] = 0u;
    __syncthreads();

    const int row = blockIdx.y;
    const float4* __restrict__ p =
        (const float4*)(x + (size_t)row * ROW_N + (size_t)blockIdx.x * CHUNK);

    #pragma unroll 8
    for (int i = tid; i < CHUNK / 4; i += BLOCK) {
        float4 v = p[i];
        bin_hit(v.x, lhw); bin_hit(v.y, lhw);
        bin_hit(v.z, lhw); bin_hit(v.w, lhw);
    }
    __syncthreads();

    // cross-wave reduce (stride 257 words -> conflict-free)
    unsigned int total = 0;
    if (tid < NBINS) {
        #pragma unroll
        for (int w = 0; w < WAVES; ++w) total += lh[w][tid];
    }

    if (!USE_WS) {
        // fallback: float atomic into pre-zeroed out (exact: multiples of
        // 2^-18, k <= 2^18 < 2^24 -> order-independent)
        if (tid < NBINS)
            atomicAdd(&out[row * NBINS + tid], (float)total * (1.0f / ROW_N));
        return;
    }

    // producer: agent-scope (sc1) stores write partials THROUGH the XCD L2 to
    // the coherence point -- coalesced vector stores, NO cache flush (the R5
    // mistake was 1536 device __threadfence L2 writebacks).
    if (tid < NBINS)
        ATOMIC_ST(&ws[((size_t)row * BPR + blockIdx.x) * NBINS + tid], total);

    // __syncthreads codegen drains vmcnt(0) per wave -> partials are AT the
    // coherence point before tid0's ticket RMW below can issue.
    __syncthreads();
    if (tid == 0) {
        unsigned int old = __hip_atomic_fetch_add(
            &ws[CTR_OFF + row], 1u, __ATOMIC_RELAXED, __HIP_MEMORY_SCOPE_AGENT);
        s_old = old;
        s_fin = (old - ATOMIC_LD(&ws[BASE_OFF + row]) == BPR - 1);
    }
    __syncthreads();

    // exactly one block per row gets the last ticket; its reads (agent-scope,
    // L2-bypassing, lane-coalesced) see all 8 completed partials.
    if (s_fin) {
        if (tid < NBINS) {
            unsigned int s = 0;
            #pragma unroll
            for (int j = 0; j < BPR; ++j)
                s += ATOMIC_LD(&ws[((size_t)row * BPR + j) * NBINS + tid]);
            // exact: s <= 2^18, scale 2^-18 -> bit-identical to reference
            out[row * NBINS + tid] = (float)s * (1.0f / ROW_N);
        }
        if (tid == 0)   // advance epoch; invariant ctr==base at call boundary
            ATOMIC_ST(&ws[BASE_OFF + row], s_old + 1);
    }
}

__global__ void nh_zero_out(float* __restrict__ out) {
    out[blockIdx.x * NBINS + threadIdx.x] = 0.0f;
}

extern "C" void kernel_launch(void* const* d_in, const int* in_sizes, int n_in,
                              void* d_out, int out_size, void* d_ws, size_t ws_size,
                              hipStream_t stream) {
    const float* x = (const float*)d_in[0];
    float* out = (float*)d_out;
    unsigned int* ws = (unsigned int*)d_ws;

    dim3 grid(BPR, ROWS);
    if (ws_size >= WS_NEEDED) {
        nh_hist<true><<<grid, BLOCK, 0, stream>>>(x, ws, out);
    } else {
        nh_zero_out<<<ROWS, NBINS, 0, stream>>>(out);
        nh_hist<false><<<grid, BLOCK, 0, stream>>>(x, ws, out);
    }
}